// Round 4
// baseline (294.507 us; speedup 1.0000x reference)
//
#include <hip/hip_runtime.h>
#include <math.h>

static inline size_t ws_align(size_t x) { return (x + 255) & ~size_t(255); }

// ---------------- degree histogram + dinv ----------------
__global__ void deg_kernel(const int* __restrict__ dst, int E, int* __restrict__ deg) {
    int e = blockIdx.x * blockDim.x + threadIdx.x;
    if (e < E) atomicAdd(&deg[dst[e]], 1);
}

__global__ void dinv_kernel(const int* __restrict__ deg, float* __restrict__ dinv, int n) {
    int i = blockIdx.x * blockDim.x + threadIdx.x;
    if (i < n) dinv[i] = rsqrtf((float)(deg[i] + 1));  // +1 self-loop
}

// ---------------- exclusive scan of deg -> rowptr (1024 elems/block) ----------
__global__ void scan1_kernel(const int* __restrict__ deg, int* __restrict__ bsum, int n) {
    __shared__ int sdata[256];
    int base = blockIdx.x * 1024;
    int sum = 0;
    for (int i = threadIdx.x; i < 1024; i += 256) {
        int idx = base + i;
        if (idx < n) sum += deg[idx];
    }
    sdata[threadIdx.x] = sum;
    __syncthreads();
    for (int s = 128; s > 0; s >>= 1) {
        if (threadIdx.x < s) sdata[threadIdx.x] += sdata[threadIdx.x + s];
        __syncthreads();
    }
    if (threadIdx.x == 0) bsum[blockIdx.x] = sdata[0];
}

__global__ void scan2_kernel(int* __restrict__ bsum, int nb) {  // nb <= 256, 1 block
    __shared__ int sdata[256];
    int v = (threadIdx.x < nb) ? bsum[threadIdx.x] : 0;
    sdata[threadIdx.x] = v;
    __syncthreads();
    for (int off = 1; off < 256; off <<= 1) {
        int t = (threadIdx.x >= off) ? sdata[threadIdx.x - off] : 0;
        __syncthreads();
        sdata[threadIdx.x] += t;
        __syncthreads();
    }
    if (threadIdx.x < nb) bsum[threadIdx.x] = sdata[threadIdx.x] - v;  // exclusive
}

__global__ void scan3_kernel(const int* __restrict__ deg, const int* __restrict__ bsum,
                             int* __restrict__ rowptr, int n) {
    __shared__ int ssum[256];
    int base = blockIdx.x * 1024 + threadIdx.x * 4;
    int v[4];
    int s = 0;
#pragma unroll
    for (int k = 0; k < 4; ++k) {
        int idx = base + k;
        v[k] = (idx < n) ? deg[idx] : 0;
        s += v[k];
    }
    ssum[threadIdx.x] = s;
    __syncthreads();
    for (int off = 1; off < 256; off <<= 1) {
        int t = (threadIdx.x >= off) ? ssum[threadIdx.x - off] : 0;
        __syncthreads();
        ssum[threadIdx.x] += t;
        __syncthreads();
    }
    int ex = (threadIdx.x > 0 ? ssum[threadIdx.x - 1] : 0) + bsum[blockIdx.x];
#pragma unroll
    for (int k = 0; k < 4; ++k) {
        int idx = base + k;
        if (idx < n) rowptr[idx] = ex;
        ex += v[k];
    }
}

// ---------------- CSR fill: adjw[pos] = {src, dinv[s]*dinv[d]} (one 8B store) -
__global__ void fill_kernel(const int* __restrict__ src, const int* __restrict__ dst,
                            const float* __restrict__ dinv, const int* __restrict__ rowptr,
                            int* __restrict__ cursor, int2* __restrict__ adjw, int E) {
    int e = blockIdx.x * blockDim.x + threadIdx.x;
    if (e >= E) return;
    int s = src[e], d = dst[e];
    int pos = rowptr[d] + atomicAdd(&cursor[d], 1);
    adjw[pos] = make_int2(s, __float_as_int(dinv[s] * dinv[d]));
}

// ---------------- dense transform: W column in registers, readlane broadcast -
// Each wave: lane owns output column `lane`; processes RPI rows at a time.
template <int FIN, int FOUT, bool RELU_IN>
__global__ void gemm_reg_kernel(const float* __restrict__ in, const float* __restrict__ W,
                                float* __restrict__ out, int n) {
    int lane = threadIdx.x & 63;
    int gwave = blockIdx.x * (blockDim.x >> 6) + (threadIdx.x >> 6);
    float w[FIN];
#pragma unroll
    for (int k = 0; k < FIN; ++k)
        w[k] = (lane < FOUT) ? W[k * FOUT + lane] : 0.0f;

    const int RPI = 4;
    int r0 = gwave * RPI;
    if (r0 >= n) return;
    float v[RPI];
    float acc[RPI];
#pragma unroll
    for (int j = 0; j < RPI; ++j) {
        int row = r0 + j;
        float t = (row < n) ? in[(size_t)row * FIN + lane] : 0.0f;
        if (RELU_IN) t = fmaxf(t, 0.0f);
        v[j] = t;
        acc[j] = 0.0f;
    }
#pragma unroll
    for (int k = 0; k < FIN; ++k) {
#pragma unroll
        for (int j = 0; j < RPI; ++j) {
            float bc = __uint_as_float(__builtin_amdgcn_readlane(__float_as_uint(v[j]), k));
            acc[j] = fmaf(bc, w[k], acc[j]);
        }
    }
#pragma unroll
    for (int j = 0; j < RPI; ++j) {
        int row = r0 + j;
        if (row < n && lane < FOUT) out[(size_t)row * FOUT + lane] = acc[j];
    }
}

// ---------------- gather-aggregate: quarter (16 lanes) per node --------------
// lane = q*16 + i ; quarter q owns node blockIdx*16 + wave*4 + q; i = float4 slot
// out[v] = h[v]*dinv[v]^2 + b + sum_{e: dst=v} h[src_e] * wgt_e
template <int F>  // F % 4 == 0, F <= 64
__global__ void gather_kernel(const int* __restrict__ rowptr, const int* __restrict__ deg,
                              const int2* __restrict__ adjw, const float* __restrict__ h,
                              const float* __restrict__ dinv, const float* __restrict__ b,
                              float* __restrict__ out, int n) {
    const int F4 = F / 4;
    int lane = threadIdx.x & 63;
    int wid = threadIdx.x >> 6;
    int q = lane >> 4;
    int i = lane & 15;
    int node = blockIdx.x * 16 + wid * 4 + q;
    if (node >= n) return;
    const bool fv = (i < F4);
    const float4* h4 = (const float4*)h;
    float di = dinv[node];
    float4 acc = make_float4(0.f, 0.f, 0.f, 0.f);
    if (fv) {
        float4 hv = h4[(size_t)node * F4 + i];
        float4 bv = ((const float4*)b)[i];
        float d2 = di * di;
        acc.x = fmaf(hv.x, d2, bv.x);
        acc.y = fmaf(hv.y, d2, bv.y);
        acc.z = fmaf(hv.z, d2, bv.z);
        acc.w = fmaf(hv.w, d2, bv.w);
    }
    int r0 = rowptr[node];
    int cnt = deg[node];
    for (int j0 = 0; j0 < cnt; j0 += 16) {
#pragma unroll
        for (int t = 0; t < 16; ++t) {
            int idx = j0 + t;
            if (idx < cnt) {              // quarter-uniform guard (no shfl needed)
                int2 ew = adjw[r0 + idx]; // same addr for all 16 lanes of quarter
                float wt = __int_as_float(ew.y);
                if (fv) {
                    float4 hv = h4[(size_t)ew.x * F4 + i];
                    acc.x = fmaf(hv.x, wt, acc.x);
                    acc.y = fmaf(hv.y, wt, acc.y);
                    acc.z = fmaf(hv.z, wt, acc.z);
                    acc.w = fmaf(hv.w, wt, acc.w);
                }
            }
        }
    }
    if (fv) ((float4*)out)[(size_t)node * F4 + i] = acc;
}

// ---------------- log_softmax over C cols, one wave per row ------------------
template <int C>
__global__ void logsoftmax_kernel(float* __restrict__ out, int n) {
    int wave = threadIdx.x >> 6;
    int lane = threadIdx.x & 63;
    int row = blockIdx.x * 4 + wave;
    if (row >= n) return;
    float v = (lane < C) ? out[(size_t)row * C + lane] : -INFINITY;
    float m = v;
#pragma unroll
    for (int off = 32; off >= 1; off >>= 1) m = fmaxf(m, __shfl_xor(m, off, 64));
    float e = (lane < C) ? expf(v - m) : 0.0f;
    float s = e;
#pragma unroll
    for (int off = 32; off >= 1; off >>= 1) s += __shfl_xor(s, off, 64);
    if (lane < C) out[(size_t)row * C + lane] = v - m - logf(s);
}

extern "C" void kernel_launch(void* const* d_in, const int* in_sizes, int n_in,
                              void* d_out, int out_size, void* d_ws, size_t ws_size,
                              hipStream_t stream) {
    const float* x  = (const float*)d_in[0];
    const int*   ei = (const int*)d_in[1];
    const float* W0 = (const float*)d_in[2];
    const float* b0 = (const float*)d_in[3];
    const float* W1 = (const float*)d_in[4];
    const float* b1 = (const float*)d_in[5];
    const float* W2 = (const float*)d_in[6];
    const float* b2 = (const float*)d_in[7];
    float* out = (float*)d_out;

    const int H   = in_sizes[3];            // 64
    const int FIN = in_sizes[2] / H;        // 64
    const int n   = in_sizes[0] / FIN;      // 50000
    const int E   = in_sizes[1] / 2;        // 800000
    (void)FIN;

    const int* srcp = ei;
    const int* dstp = ei + E;

    char* ws = (char*)d_ws;
    size_t off = 0;
    int*   deg    = (int*)(ws + off);   off += ws_align((size_t)n * 4);
    int*   cursor = (int*)(ws + off);   off += ws_align((size_t)n * 4);
    int*   rowptr = (int*)(ws + off);   off += ws_align((size_t)n * 4);
    int*   bsum   = (int*)(ws + off);   off += ws_align(256 * 4);
    float* dinv   = (float*)(ws + off); off += ws_align((size_t)n * 4);
    int2*  adjw   = (int2*)(ws + off);  off += ws_align((size_t)E * 8);
    float* buf0   = (float*)(ws + off); off += ws_align((size_t)n * H * 4);
    float* buf1   = (float*)(ws + off); off += ws_align((size_t)n * H * 4);

    // zero deg + cursor (adjacent -> single memset covers both)
    hipMemsetAsync(deg, 0, ws_align((size_t)n * 4) * 2, stream);

    // CSR build
    deg_kernel<<<(E + 255) / 256, 256, 0, stream>>>(dstp, E, deg);
    dinv_kernel<<<(n + 255) / 256, 256, 0, stream>>>(deg, dinv, n);
    int nscan = (n + 1023) / 1024;  // 49
    scan1_kernel<<<nscan, 256, 0, stream>>>(deg, bsum, n);
    scan2_kernel<<<1, 256, 0, stream>>>(bsum, nscan);
    scan3_kernel<<<nscan, 256, 0, stream>>>(deg, bsum, rowptr, n);
    fill_kernel<<<(E + 255) / 256, 256, 0, stream>>>(srcp, dstp, dinv, rowptr, cursor, adjw, E);

    const int RPI = 4;  // rows per wave in gemm
    int gemm_grid = (n + 4 * RPI - 1) / (4 * RPI);   // 4 waves/block
    int node_grid = (n + 15) / 16;                   // 16 nodes/block

    // layer 0
    gemm_reg_kernel<64, 64, false><<<gemm_grid, 256, 0, stream>>>(x, W0, buf0, n);
    gather_kernel<64><<<node_grid, 256, 0, stream>>>(rowptr, deg, adjw, buf0, dinv, b0, buf1, n);
    // layer 1
    gemm_reg_kernel<64, 64, true><<<gemm_grid, 256, 0, stream>>>(buf1, W1, buf0, n);
    gather_kernel<64><<<node_grid, 256, 0, stream>>>(rowptr, deg, adjw, buf0, dinv, b1, buf1, n);
    // layer 2
    gemm_reg_kernel<64, 40, true><<<gemm_grid, 256, 0, stream>>>(buf1, W2, buf0, n);
    gather_kernel<40><<<node_grid, 256, 0, stream>>>(rowptr, deg, adjw, buf0, dinv, b2, out, n);
    logsoftmax_kernel<40><<<(n + 3) / 4, 256, 0, stream>>>(out, n);
}